// Round 15
// baseline (177.555 us; speedup 1.0000x reference)
//
#include <hip/hip_runtime.h>

#define NN 50000
#define NE 1600000
#define DF 128
#define NB 1250     // buckets
#define BSZ 40      // dst nodes per bucket (NB*BSZ == NN)
#define CAP 1664    // per-bucket capacity; load 1280 +/- 36 -> +10.7 sigma
#define NWGP 64     // FAT partition workgroups: long runs, few descriptors
#define CHKP 25000  // edges per partition wg (64*25000 == NE)
#define NBF 3125    // norm blocks: 16 rows each (512 thr, float4)

static __device__ __forceinline__ float bflo(unsigned int u) {
    unsigned int v = u << 16; float f; __builtin_memcpy(&f, &v, 4); return f;
}
static __device__ __forceinline__ float bfhi(unsigned int u) {
    unsigned int v = u & 0xFFFF0000u; float f; __builtin_memcpy(&f, &v, 4); return f;
}
static __device__ __forceinline__ unsigned int f2bf(float f) {   // RNE, low 16 bits
    unsigned int u; __builtin_memcpy(&u, &f, 4);
    u += 0x7FFFu + ((u >> 16) & 1u);
    return u >> 16;
}

// Block-wide exclusive scan, 512 threads (8 waves). 2 barriers.
static __device__ __forceinline__ int block_excl_scan512(int v, int t, int* wsum8) {
    int lane = t & 63, wv = t >> 6;
    int s = v;
    #pragma unroll
    for (int off = 1; off < 64; off <<= 1) {
        int u = __shfl_up(s, off);
        if (lane >= off) s += u;
    }
    if (lane == 63) wsum8[wv] = s;
    __syncthreads();
    int add = 0;
    #pragma unroll
    for (int w = 0; w < 8; ++w) add += (w < wv) ? wsum8[w] : 0;
    __syncthreads();
    return s + add - v;      // exclusive
}

// ---------------------------------------------------------------------------
// K1 (partition): 64 blocks x 512 thr; each counting-sorts its 25000 edges by
// bucket entirely in a 100 KB LDS slab, then flushes COALESCED into its
// private pairs slab. desc row descG[wg][b] = (runoff<<16 | runlen) written
// coalesced (off<=25000<2^15... fits 16 bits: 25000<65536; len ~20). Long
// runs (~20 edges) make K2's merge reads ~full-line. No global atomics.
// ---------------------------------------------------------------------------
__global__ __launch_bounds__(512)
void k_part(const int* __restrict__ ei,
            unsigned int* __restrict__ descG,
            unsigned int* __restrict__ pairs) {
    __shared__ int wsum8[8];
    __shared__ int cntL[NB];
    __shared__ int offL[NB];
    __shared__ unsigned int stg[CHKP];          // 100 KB
    int wg = blockIdx.x, t = threadIdx.x;
    const int* srcp = ei + wg * CHKP;
    const int* dstp = ei + NE + wg * CHKP;
    for (int i = t; i < NB; i += 512) cntL[i] = 0;
    __syncthreads();
    #pragma unroll 4
    for (int i = t; i < CHKP; i += 512) atomicAdd(&cntL[dstp[i] / BSZ], 1);
    __syncthreads();
    {   // exclusive scan of cntL[0..NB): 3 consecutive values per thread
        int base = t * 3;
        int loc[3];
        int s = 0;
        #pragma unroll
        for (int q = 0; q < 3; ++q) {
            int idx = base + q;
            int v = (idx < NB) ? cntL[idx] : 0;
            loc[q] = s;
            s += v;
        }
        int ex = block_excl_scan512(s, t, wsum8);
        #pragma unroll
        for (int q = 0; q < 3; ++q) {
            int idx = base + q;
            if (idx < NB) offL[idx] = ex + loc[q];
        }
    }
    __syncthreads();
    for (int i = t; i < NB; i += 512)
        descG[(size_t)wg * NB + i] = ((unsigned int)offL[i] << 16) | (unsigned int)cntL[i];
    __syncthreads();                 // all offL reads done before cursor bumps
    #pragma unroll 2
    for (int i = t; i < CHKP; i += 512) {
        int src = srcp[i];
        int dst = dstp[i];
        int b = dst / BSZ;
        int pos = atomicAdd(&offL[b], 1);
        stg[pos] = ((unsigned int)(dst - b * BSZ) << 16) | (unsigned int)src;
    }
    __syncthreads();
    unsigned int* chunk = pairs + (size_t)wg * CHKP;
    #pragma unroll 4
    for (int i = t; i < CHKP; i += 512) chunk[i] = stg[i];
}

// ---------------------------------------------------------------------------
// K2 (norm): 512 thr, float4; each 32-lane half-wave owns one row.
// xn_bf = bf16(x * rsqrt(max(ss, eps^2))), norm = ||x|| (smooth ->0).
// Softmax later shifts by the constant |beta| (exact by shift-invariance;
// the self-loop keeps every denominator >= exp(-2|beta|) > 0).
// ---------------------------------------------------------------------------
__global__ __launch_bounds__(512)
void k_norm(const float* __restrict__ x,
            unsigned int* __restrict__ xn_bf,
            float* __restrict__ norm) {
    int t = threadIdx.x;
    int l32 = t & 31;
    int node = blockIdx.x * 16 + (t >> 5);
    float4 v = ((const float4*)(x + (size_t)node * DF))[l32];
    float ss = v.x * v.x + v.y * v.y + v.z * v.z + v.w * v.w;
    #pragma unroll
    for (int m = 1; m < 32; m <<= 1) ss += __shfl_xor(ss, m);   // 32-lane group
    float rinv = rsqrtf(fmaxf(ss, 1e-24f));
    uint2 p;
    p.x = (f2bf(v.y * rinv) << 16) | f2bf(v.x * rinv);
    p.y = (f2bf(v.w * rinv) << 16) | f2bf(v.z * rinv);
    ((uint2*)(xn_bf + (size_t)node * 64))[l32] = p;
    if (l32 == 0) norm[node] = ss * rinv;
}

// ---------------------------------------------------------------------------
// K3 (fused build + gather): one block (256 thr) per bucket (~15 KB LDS ->
// 8 blocks/CU).
//  Merge: wave 0 reads the 64 descriptors (64 lines/block total) and
//  wave-scans run bases; 16 groups x 16 lanes copy the ~20-edge runs into
//  rawL (~full-line reads). Build: LDS hist over 40 local dst, single-wave
//  scan -> rp, LDS fill of colL packing bf16(norm[src]). Gather: wave w
//  handles local nodes w, w+4,...; 4 groups x 16 lanes, 2-edge software
//  pipeline; col reads are LDS.
// ---------------------------------------------------------------------------
__global__ __launch_bounds__(256)
void k_build_gather(const unsigned int* __restrict__ xn_bf,
                    const float* __restrict__ norm,
                    const unsigned int* __restrict__ descG,
                    const unsigned int* __restrict__ pairs,
                    const float* __restrict__ beta_p,
                    float* __restrict__ out) {
    __shared__ int lenS[NWGP], offS[NWGP], rbase[NWGP];
    __shared__ unsigned int rawL[CAP];
    __shared__ unsigned int colL[CAP];
    __shared__ int hist[BSZ];
    __shared__ int rp[BSZ + 1];
    __shared__ int stot;
    int b = blockIdx.x, t = threadIdx.x;

    if (t < NWGP) {                  // wave 0: desc read + 64-lane scan
        unsigned int d = descG[(size_t)t * NB + b];
        int len = (int)(d & 0xFFFFu);
        int s = len;
        #pragma unroll
        for (int off = 1; off < 64; off <<= 1) {
            int u = __shfl_up(s, off);
            if (t >= off) s += u;
        }
        lenS[t] = len;
        offS[t] = (int)(d >> 16);
        rbase[t] = s - len;          // exclusive
        if (t == NWGP - 1) stot = s;
    }
    if (t >= 64 && t < 64 + BSZ) hist[t - 64] = 0;
    __syncthreads();
    int cnt = stot;
    if (cnt > CAP) cnt = CAP;        // never fires (memory safety)

    // cooperative run copy: 16 groups x 16 lanes over 64 runs (4 iterations)
    int g16 = t >> 4, l16 = t & 15;
    for (int r = g16; r < NWGP; r += 16) {
        int len = lenS[r];
        int rb = rbase[r];
        const unsigned int* sp = pairs + (size_t)r * CHKP + offS[r];
        for (int q = l16; q < len; q += 16) {
            int pos = rb + q;
            if (pos < CAP) rawL[pos] = sp[q];
        }
    }
    __syncthreads();
    for (int i = t; i < cnt; i += 256) atomicAdd(&hist[rawL[i] >> 16], 1);
    __syncthreads();
    if (t < 64) {                    // single-wave scan (BSZ=40 < 64)
        int v = (t < BSZ) ? hist[t] : 0;
        int s = v;
        #pragma unroll
        for (int off = 1; off < 64; off <<= 1) {
            int u = __shfl_up(s, off);
            if (t >= off) s += u;
        }
        if (t < BSZ) { rp[t + 1] = s; hist[t] = s - v; }   // cursor = exclusive
        if (t == 0) rp[0] = 0;
    }
    __syncthreads();
    for (int i = t; i < cnt; i += 256) {
        unsigned int p = rawL[i];
        unsigned int src = p & 0xFFFFu;
        int pos = atomicAdd(&hist[p >> 16], 1);
        colL[pos] = (f2bf(norm[src]) << 16) | src;
    }
    __syncthreads();

    // ---- gather (col/rp from LDS) ----
    int lane = t & 63;
    int w = t >> 6;
    int j = lane & 15;
    int g = lane >> 4;
    float beta = beta_p[0];
    float c = -fabsf(beta);
    for (int ln = w; ln < BSZ; ln += 4) {
        int node = b * BSZ + ln;
        uint4 du = ((const uint4*)(xn_bf + (size_t)node * 64))[j];
        float xd[8];
        #pragma unroll
        for (int q = 0; q < 4; ++q) {
            unsigned int u = (&du.x)[q];
            xd[2 * q]     = bflo(u);
            xd[2 * q + 1] = bfhi(u);
        }
        float acc[8] = {0.f, 0.f, 0.f, 0.f, 0.f, 0.f, 0.f, 0.f};
        float ssum = 0.f;
        int b0 = rp[ln], b1 = rp[ln + 1];

        int k = b0 + g;
        int kA = (k     < b1) ? k     : 0;
        int kB = (k + 4 < b1) ? k + 4 : 0;
        unsigned int pA = colL[kA];
        unsigned int pB = colL[kB];
        uint4 rA = ((const uint4*)(xn_bf + (size_t)(pA & 0xFFFFu) * 64))[j];
        uint4 rB = ((const uint4*)(xn_bf + (size_t)(pB & 0xFFFFu) * 64))[j];

        for (; k < b1; k += 8) {
            int kC = (k +  8 < b1) ? k +  8 : 0;
            int kD = (k + 12 < b1) ? k + 12 : 0;
            unsigned int pC = colL[kC];
            unsigned int pD = colL[kD];
            uint4 rC = ((const uint4*)(xn_bf + (size_t)(pC & 0xFFFFu) * 64))[j];
            uint4 rD = ((const uint4*)(xn_bf + (size_t)(pD & 0xFFFFu) * 64))[j];
            {   // edge A (always valid: k < b1)
                float xs[8];
                #pragma unroll
                for (int q = 0; q < 4; ++q) {
                    unsigned int u = (&rA.x)[q];
                    xs[2 * q]     = bflo(u);
                    xs[2 * q + 1] = bfhi(u);
                }
                float dot = 0.f;
                #pragma unroll
                for (int q = 0; q < 8; ++q) dot = fmaf(xd[q], xs[q], dot);
                dot += __shfl_xor(dot, 1);
                dot += __shfl_xor(dot, 2);
                dot += __shfl_xor(dot, 4);
                dot += __shfl_xor(dot, 8);
                float e = __expf(fmaf(beta, dot, c));
                ssum += e;
                float wgt = e * bfhi(pA);
                #pragma unroll
                for (int q = 0; q < 8; ++q) acc[q] = fmaf(wgt, xs[q], acc[q]);
            }
            {   // edge B (valid iff k+4 < b1)
                float xs[8];
                #pragma unroll
                for (int q = 0; q < 4; ++q) {
                    unsigned int u = (&rB.x)[q];
                    xs[2 * q]     = bflo(u);
                    xs[2 * q + 1] = bfhi(u);
                }
                float dot = 0.f;
                #pragma unroll
                for (int q = 0; q < 8; ++q) dot = fmaf(xd[q], xs[q], dot);
                dot += __shfl_xor(dot, 1);
                dot += __shfl_xor(dot, 2);
                dot += __shfl_xor(dot, 4);
                dot += __shfl_xor(dot, 8);
                float e = __expf(fmaf(beta, dot, c));
                e = (k + 4 < b1) ? e : 0.f;
                ssum += e;
                float wgt = e * bfhi(pB);
                #pragma unroll
                for (int q = 0; q < 8; ++q) acc[q] = fmaf(wgt, xs[q], acc[q]);
            }
            pA = pC; pB = pD; rA = rC; rB = rD;
        }

        ssum += __shfl_xor(ssum, 16);
        ssum += __shfl_xor(ssum, 32);
        #pragma unroll
        for (int q = 0; q < 8; ++q) {
            acc[q] += __shfl_xor(acc[q], 16);
            acc[q] += __shfl_xor(acc[q], 32);
        }
        float e_self = __expf(beta + c);          // self-loop, cos = 1
        ssum += e_self;
        float wsl = e_self * norm[node];
        #pragma unroll
        for (int q = 0; q < 8; ++q) acc[q] = fmaf(wsl, xd[q], acc[q]);

        if (g == 0) {
            float inv = 1.0f / ssum;
            float4 o0, o1;
            o0.x = fmaxf(0.f, acc[0] * inv); o0.y = fmaxf(0.f, acc[1] * inv);
            o0.z = fmaxf(0.f, acc[2] * inv); o0.w = fmaxf(0.f, acc[3] * inv);
            o1.x = fmaxf(0.f, acc[4] * inv); o1.y = fmaxf(0.f, acc[5] * inv);
            o1.z = fmaxf(0.f, acc[6] * inv); o1.w = fmaxf(0.f, acc[7] * inv);
            float4* op = (float4*)(out + (size_t)node * DF + 8 * j);
            op[0] = o0;
            op[1] = o1;
        }
    }
}

extern "C" void kernel_launch(void* const* d_in, const int* in_sizes, int n_in,
                              void* d_out, int out_size, void* d_ws, size_t ws_size,
                              hipStream_t stream) {
    const float* x    = (const float*)d_in[0];   // fp32 [NN*DF]
    const float* beta = (const float*)d_in[1];   // fp32 [1]
    const int*   ei   = (const int*)d_in[2];     // int32 [2*NE]
    float*       out  = (float*)d_out;           // fp32 [NN*DF]

    // workspace layout (bytes), total ~19.7 MiB:
    char* ws = (char*)d_ws;
    unsigned int* xn_bf = (unsigned int*)ws;                  // NN*64*4 = 12,800,000
    float* norm = (float*)(ws + 12800000);                    // NN*4    =    200,000
    unsigned int* descG = (unsigned int*)(ws + 13000000);     // NWGP*NB*4 = 320,000
    unsigned int* pairs = (unsigned int*)(ws + 13320000);     // NE*4 = 6,400,000

    k_part        <<<NWGP, 512, 0, stream>>>(ei, descG, pairs);
    k_norm        <<<NBF,  512, 0, stream>>>(x, xn_bf, norm);
    k_build_gather<<<NB,   256, 0, stream>>>(xn_bf, norm, descG, pairs, beta, out);
}

// Round 16
// 156.134 us; speedup vs baseline: 1.1372x; 1.1372x over previous
//
#include <hip/hip_runtime.h>

#define NN 50000
#define NE 1600000
#define DF 128
#define NB 1250     // buckets
#define BSZ 40      // dst nodes per bucket (NB*BSZ == NN)
#define CAP 1664    // per-bucket capacity; load 1280 +/- 36 -> +10.7 sigma
#define NWGP 256    // partition workgroups: 1 per CU, runs ~5 edges
#define CHKP 6250   // edges per partition wg (256*6250 == NE)
#define NBF 3125    // norm blocks: 16 rows each (512 thr, float4)

static __device__ __forceinline__ float bflo(unsigned int u) {
    unsigned int v = u << 16; float f; __builtin_memcpy(&f, &v, 4); return f;
}
static __device__ __forceinline__ float bfhi(unsigned int u) {
    unsigned int v = u & 0xFFFF0000u; float f; __builtin_memcpy(&f, &v, 4); return f;
}
static __device__ __forceinline__ unsigned int f2bf(float f) {   // RNE, low 16 bits
    unsigned int u; __builtin_memcpy(&u, &f, 4);
    u += 0x7FFFu + ((u >> 16) & 1u);
    return u >> 16;
}

// Block-wide exclusive scan, 512 threads (8 waves). 2 barriers.
static __device__ __forceinline__ int block_excl_scan512(int v, int t, int* wsum8) {
    int lane = t & 63, wv = t >> 6;
    int s = v;
    #pragma unroll
    for (int off = 1; off < 64; off <<= 1) {
        int u = __shfl_up(s, off);
        if (lane >= off) s += u;
    }
    if (lane == 63) wsum8[wv] = s;
    __syncthreads();
    int add = 0;
    #pragma unroll
    for (int w = 0; w < 8; ++w) add += (w < wv) ? wsum8[w] : 0;
    __syncthreads();
    return s + add - v;      // exclusive
}

// Block-wide exclusive scan, 256 threads (4 waves). 2 barriers.
static __device__ __forceinline__ int block_excl_scan256(int v, int t, int* wsum4) {
    int lane = t & 63, wv = t >> 6;
    int s = v;
    #pragma unroll
    for (int off = 1; off < 64; off <<= 1) {
        int u = __shfl_up(s, off);
        if (lane >= off) s += u;
    }
    if (lane == 63) wsum4[wv] = s;
    __syncthreads();
    int add = 0;
    #pragma unroll
    for (int w = 0; w < 4; ++w) add += (w < wv) ? wsum4[w] : 0;
    __syncthreads();
    return s + add - v;      // exclusive
}

// ---------------------------------------------------------------------------
// K1 (fused; partition blocks [0,NWGP) dispatch first — exactly one per CU,
// every CU busy — with norm blocks draining behind):
//  partition: wg-local counting sort of 6250 edges by bucket in a 25 KB LDS
//             slab; sorted records streamed out COALESCED into the wg's
//             private pairs slab; packed descriptor row descG[wg][b] =
//             (runoff<<16 | runlen), coalesced. No global atomics.
//  norm:      float4: 32 lanes/row, 16 rows/block: xn_bf = bf16(x*rsqrt(ss)),
//             norm = ||x||. Softmax later shifts by the constant |beta|
//             (exact by shift-invariance; the self-loop keeps every
//             denominator >= exp(-2|beta|) > 0).
// ---------------------------------------------------------------------------
__global__ __launch_bounds__(512)
void k_norm_part(const float* __restrict__ x,
                 const int* __restrict__ ei,
                 unsigned int* __restrict__ xn_bf,
                 float* __restrict__ norm,
                 unsigned int* __restrict__ descG,
                 unsigned int* __restrict__ pairs) {
    __shared__ int wsum8[8];
    __shared__ int cntL[NB];
    __shared__ int offL[NB];
    __shared__ unsigned int stg[CHKP];          // 25 KB
    int t = threadIdx.x;
    if (blockIdx.x >= NWGP) {
        int l32 = t & 31;
        int node = (blockIdx.x - NWGP) * 16 + (t >> 5);
        float4 v = ((const float4*)(x + (size_t)node * DF))[l32];
        float ss = v.x * v.x + v.y * v.y + v.z * v.z + v.w * v.w;
        #pragma unroll
        for (int m = 1; m < 32; m <<= 1) ss += __shfl_xor(ss, m);  // 32-lane group
        float rinv = rsqrtf(fmaxf(ss, 1e-24f));
        uint2 p;
        p.x = (f2bf(v.y * rinv) << 16) | f2bf(v.x * rinv);
        p.y = (f2bf(v.w * rinv) << 16) | f2bf(v.z * rinv);
        ((uint2*)(xn_bf + (size_t)node * 64))[l32] = p;
        if (l32 == 0) norm[node] = ss * rinv;        // == ||x||, smooth at 0
        return;
    }
    int wg = blockIdx.x;
    const int* srcp = ei + wg * CHKP;
    const int* dstp = ei + NE + wg * CHKP;
    for (int i = t; i < NB; i += 512) cntL[i] = 0;
    __syncthreads();
    #pragma unroll 4
    for (int i = t; i < CHKP; i += 512) atomicAdd(&cntL[dstp[i] / BSZ], 1);
    __syncthreads();
    {   // exclusive scan of cntL[0..NB): 3 consecutive values per thread
        int base = t * 3;
        int loc[3];
        int s = 0;
        #pragma unroll
        for (int q = 0; q < 3; ++q) {
            int idx = base + q;
            int v = (idx < NB) ? cntL[idx] : 0;
            loc[q] = s;
            s += v;
        }
        int ex = block_excl_scan512(s, t, wsum8);
        #pragma unroll
        for (int q = 0; q < 3; ++q) {
            int idx = base + q;
            if (idx < NB) offL[idx] = ex + loc[q];
        }
    }
    __syncthreads();
    // packed descriptor row, coalesced (off,cnt <= 6250 both fit 16 bits)
    for (int i = t; i < NB; i += 512)
        descG[(size_t)wg * NB + i] = ((unsigned int)offL[i] << 16) | (unsigned int)cntL[i];
    __syncthreads();                 // all offL reads done before cursor bumps
    #pragma unroll 2
    for (int i = t; i < CHKP; i += 512) {
        int src = srcp[i];
        int dst = dstp[i];
        int b = dst / BSZ;
        int pos = atomicAdd(&offL[b], 1);
        stg[pos] = ((unsigned int)(dst - b * BSZ) << 16) | (unsigned int)src;
    }
    __syncthreads();
    unsigned int* chunk = pairs + (size_t)wg * CHKP;
    #pragma unroll 4
    for (int i = t; i < CHKP; i += 512) chunk[i] = stg[i];
}

// ---------------------------------------------------------------------------
// K2 (fused build + gather): one block (256 thr) per bucket (~17 KB LDS ->
// 8 blocks/CU).
//  Merge: all 256 threads read one descriptor each (256 lines/block),
//  block-scan -> run bases; 32 groups x 8 lanes copy the ~5-edge runs into
//  rawL. Build: LDS hist over 40 local dst, single-wave scan -> rp, LDS fill
//  of colL packing bf16(norm[src]). Gather: wave w handles local nodes
//  w, w+4,...; 4 groups x 16 lanes, 2-edge software pipeline; col reads LDS.
// ---------------------------------------------------------------------------
__global__ __launch_bounds__(256)
void k_build_gather(const unsigned int* __restrict__ xn_bf,
                    const float* __restrict__ norm,
                    const unsigned int* __restrict__ descG,
                    const unsigned int* __restrict__ pairs,
                    const float* __restrict__ beta_p,
                    float* __restrict__ out) {
    __shared__ int wsum4[4];
    __shared__ int lenS[NWGP], offS[NWGP], rbase[NWGP];
    __shared__ unsigned int rawL[CAP];
    __shared__ unsigned int colL[CAP];
    __shared__ int hist[BSZ];
    __shared__ int rp[BSZ + 1];
    __shared__ int stot;
    int b = blockIdx.x, t = threadIdx.x;

    {   // desc read (one per thread, 256 runs) + block scan
        unsigned int d = descG[(size_t)t * NB + b];
        int len = (int)(d & 0xFFFFu);
        int ex = block_excl_scan256(len, t, wsum4);
        lenS[t] = len;
        offS[t] = (int)(d >> 16);
        rbase[t] = ex;
        if (t == 255) stot = ex + len;
    }
    if (t < BSZ) hist[t] = 0;
    __syncthreads();
    int cnt = stot;
    if (cnt > CAP) cnt = CAP;        // never fires (memory safety)

    // cooperative run copy: 32 groups x 8 lanes over 256 runs (8 iterations)
    int g8 = t >> 3, l8 = t & 7;
    for (int r = g8; r < NWGP; r += 32) {
        int len = lenS[r];
        int rb = rbase[r];
        const unsigned int* sp = pairs + (size_t)r * CHKP + offS[r];
        for (int q = l8; q < len; q += 8) {
            int pos = rb + q;
            if (pos < CAP) rawL[pos] = sp[q];
        }
    }
    __syncthreads();
    for (int i = t; i < cnt; i += 256) atomicAdd(&hist[rawL[i] >> 16], 1);
    __syncthreads();
    if (t < 64) {                    // single-wave scan (BSZ=40 < 64)
        int v = (t < BSZ) ? hist[t] : 0;
        int s = v;
        #pragma unroll
        for (int off = 1; off < 64; off <<= 1) {
            int u = __shfl_up(s, off);
            if (t >= off) s += u;
        }
        if (t < BSZ) { rp[t + 1] = s; hist[t] = s - v; }   // cursor = exclusive
        if (t == 0) rp[0] = 0;
    }
    __syncthreads();
    for (int i = t; i < cnt; i += 256) {
        unsigned int p = rawL[i];
        unsigned int src = p & 0xFFFFu;
        int pos = atomicAdd(&hist[p >> 16], 1);
        colL[pos] = (f2bf(norm[src]) << 16) | src;
    }
    __syncthreads();

    // ---- gather (col/rp from LDS) ----
    int lane = t & 63;
    int w = t >> 6;
    int j = lane & 15;
    int g = lane >> 4;
    float beta = beta_p[0];
    float c = -fabsf(beta);
    for (int ln = w; ln < BSZ; ln += 4) {
        int node = b * BSZ + ln;
        uint4 du = ((const uint4*)(xn_bf + (size_t)node * 64))[j];
        float xd[8];
        #pragma unroll
        for (int q = 0; q < 4; ++q) {
            unsigned int u = (&du.x)[q];
            xd[2 * q]     = bflo(u);
            xd[2 * q + 1] = bfhi(u);
        }
        float acc[8] = {0.f, 0.f, 0.f, 0.f, 0.f, 0.f, 0.f, 0.f};
        float ssum = 0.f;
        int b0 = rp[ln], b1 = rp[ln + 1];

        int k = b0 + g;
        int kA = (k     < b1) ? k     : 0;
        int kB = (k + 4 < b1) ? k + 4 : 0;
        unsigned int pA = colL[kA];
        unsigned int pB = colL[kB];
        uint4 rA = ((const uint4*)(xn_bf + (size_t)(pA & 0xFFFFu) * 64))[j];
        uint4 rB = ((const uint4*)(xn_bf + (size_t)(pB & 0xFFFFu) * 64))[j];

        for (; k < b1; k += 8) {
            int kC = (k +  8 < b1) ? k +  8 : 0;
            int kD = (k + 12 < b1) ? k + 12 : 0;
            unsigned int pC = colL[kC];
            unsigned int pD = colL[kD];
            uint4 rC = ((const uint4*)(xn_bf + (size_t)(pC & 0xFFFFu) * 64))[j];
            uint4 rD = ((const uint4*)(xn_bf + (size_t)(pD & 0xFFFFu) * 64))[j];
            {   // edge A (always valid: k < b1)
                float xs[8];
                #pragma unroll
                for (int q = 0; q < 4; ++q) {
                    unsigned int u = (&rA.x)[q];
                    xs[2 * q]     = bflo(u);
                    xs[2 * q + 1] = bfhi(u);
                }
                float dot = 0.f;
                #pragma unroll
                for (int q = 0; q < 8; ++q) dot = fmaf(xd[q], xs[q], dot);
                dot += __shfl_xor(dot, 1);
                dot += __shfl_xor(dot, 2);
                dot += __shfl_xor(dot, 4);
                dot += __shfl_xor(dot, 8);
                float e = __expf(fmaf(beta, dot, c));
                ssum += e;
                float wgt = e * bfhi(pA);
                #pragma unroll
                for (int q = 0; q < 8; ++q) acc[q] = fmaf(wgt, xs[q], acc[q]);
            }
            {   // edge B (valid iff k+4 < b1)
                float xs[8];
                #pragma unroll
                for (int q = 0; q < 4; ++q) {
                    unsigned int u = (&rB.x)[q];
                    xs[2 * q]     = bflo(u);
                    xs[2 * q + 1] = bfhi(u);
                }
                float dot = 0.f;
                #pragma unroll
                for (int q = 0; q < 8; ++q) dot = fmaf(xd[q], xs[q], dot);
                dot += __shfl_xor(dot, 1);
                dot += __shfl_xor(dot, 2);
                dot += __shfl_xor(dot, 4);
                dot += __shfl_xor(dot, 8);
                float e = __expf(fmaf(beta, dot, c));
                e = (k + 4 < b1) ? e : 0.f;
                ssum += e;
                float wgt = e * bfhi(pB);
                #pragma unroll
                for (int q = 0; q < 8; ++q) acc[q] = fmaf(wgt, xs[q], acc[q]);
            }
            pA = pC; pB = pD; rA = rC; rB = rD;
        }

        ssum += __shfl_xor(ssum, 16);
        ssum += __shfl_xor(ssum, 32);
        #pragma unroll
        for (int q = 0; q < 8; ++q) {
            acc[q] += __shfl_xor(acc[q], 16);
            acc[q] += __shfl_xor(acc[q], 32);
        }
        float e_self = __expf(beta + c);          // self-loop, cos = 1
        ssum += e_self;
        float wsl = e_self * norm[node];
        #pragma unroll
        for (int q = 0; q < 8; ++q) acc[q] = fmaf(wsl, xd[q], acc[q]);

        if (g == 0) {
            float inv = 1.0f / ssum;
            float4 o0, o1;
            o0.x = fmaxf(0.f, acc[0] * inv); o0.y = fmaxf(0.f, acc[1] * inv);
            o0.z = fmaxf(0.f, acc[2] * inv); o0.w = fmaxf(0.f, acc[3] * inv);
            o1.x = fmaxf(0.f, acc[4] * inv); o1.y = fmaxf(0.f, acc[5] * inv);
            o1.z = fmaxf(0.f, acc[6] * inv); o1.w = fmaxf(0.f, acc[7] * inv);
            float4* op = (float4*)(out + (size_t)node * DF + 8 * j);
            op[0] = o0;
            op[1] = o1;
        }
    }
}

extern "C" void kernel_launch(void* const* d_in, const int* in_sizes, int n_in,
                              void* d_out, int out_size, void* d_ws, size_t ws_size,
                              hipStream_t stream) {
    const float* x    = (const float*)d_in[0];   // fp32 [NN*DF]
    const float* beta = (const float*)d_in[1];   // fp32 [1]
    const int*   ei   = (const int*)d_in[2];     // int32 [2*NE]
    float*       out  = (float*)d_out;           // fp32 [NN*DF]

    // workspace layout (bytes), total ~20.7 MiB:
    char* ws = (char*)d_ws;
    unsigned int* xn_bf = (unsigned int*)ws;                  // NN*64*4 = 12,800,000
    float* norm = (float*)(ws + 12800000);                    // NN*4    =    200,000
    unsigned int* descG = (unsigned int*)(ws + 13000000);     // NWGP*NB*4 = 1,280,000
    unsigned int* pairs = (unsigned int*)(ws + 14280000);     // NE*4 = 6,400,000

    k_norm_part  <<<NWGP + NBF, 512, 0, stream>>>(x, ei, xn_bf, norm, descG, pairs);
    k_build_gather<<<NB,        256, 0, stream>>>(xn_bf, norm, descG, pairs, beta, out);
}